// Round 6
// baseline (126.758 us; speedup 1.0000x reference)
//
#include <hip/hip_runtime.h>
#include <hip/hip_fp16.h>

#define C_COLS 8192

// ---------------------------------------------------------------------------
// FUSED kernel (R6): the R5 table kernel is folded in, computed redundantly
// per block by lanes 0..15 while the block's global loads are in flight.
// All decision arithmetic is BIT-IDENTICAL to the passing R5 kernel:
//   table: f64 ndtri (A&S seed + 3 Newton steps on Phi via erfc) -> f32 ->
//          f32 divide by max|z| -> fp16 RNE round-trip
//   x_norm: s2r = 2.0f/den (== 2*round32(1/den) exactly); p = (x-bm)*s2r;
//           xn = p - 1.0f   (separate sub, contract OFF)
//   argmin: 16-way f32 |xn - t| scan, strict '<' keeps first min
//   scales: recip-hoisted (sc-s_min)*round32(1/sden)*255, rintf (RNE)
// One workgroup (256 thr = 4 waves) per row; wave w owns floats
// [w*2048, w*2048+2048); each 16-lane group holds one 64-elem quant-block.
// ---------------------------------------------------------------------------
__global__ __launch_bounds__(256) void nf4_fused_kernel(
        const float* __restrict__ x, float* __restrict__ out) {
#pragma clang fp contract(off)
    __shared__ double zf[16];
    __shared__ float  stbl[16];
    __shared__ float  smin[4], smax[4];

    const int row  = blockIdx.x;
    const int wave = threadIdx.x >> 6;
    const int lane = threadIdx.x & 63;
    const long base = (long)row * C_COLS + (long)wave * 2048;
    const float4* __restrict__ xin4 = reinterpret_cast<const float4*>(x + base);
    float4* __restrict__ out4       = reinterpret_cast<float4*>(out + base);

    // ---- issue all global loads first: 8 outstanding dwordx4 per lane ----
    float4 v[8];
#pragma unroll
    for (int k = 0; k < 8; ++k) v[k] = xin4[k * 64 + lane];   // coalesced

    // ---- table phase (lanes 0..15 of wave 0), hides under load latency ----
    if (threadIdx.x < 16) {
        const int i = threadIdx.x;
        double p  = (2.0 * i + 1.0) / 32.0;            // exact in binary
        double pl = (p < 0.5) ? p : 1.0 - p;
        double t  = sqrt(-2.0 * log(pl));
        // A&S 26.2.22 seed, then Newton on Phi(z)-p to ~2e-16 (scipy-exact)
        double z  = t - (2.30753 + 0.27061 * t) / (1.0 + t * (0.99229 + 0.04481 * t));
        if (p < 0.5) z = -z;
        for (int it = 0; it < 3; ++it) {
            double Phi = 0.5 * erfc(-z * 0.7071067811865476);
            double phi = 0.3989422804014326779 * exp(-0.5 * z * z);
            z -= (Phi - p) / phi;
        }
        zf[i] = z;
    }
    __syncthreads();                                   // zf visible
    if (threadIdx.x < 16) {
        float zi = (float)zf[threadIdx.x];             // scipy 'f' loop cast
        float qmax = 0.0f;
        for (int j = 0; j < 16; ++j) qmax = fmaxf(qmax, fabsf((float)zf[j]));
        float qn = zi / qmax;                          // IEEE f32 divide
        stbl[threadIdx.x] = __half2float(__float2half(qn));  // fp16 RNE
    }

    // ---- block min/max (16-lane group = one 64-elem quant-block) ----
    float bmin[8], bmax[8], srec[8];
    float tmin = 3.4e38f, tmax = -3.4e38f;
#pragma unroll
    for (int k = 0; k < 8; ++k) {
        float m = fminf(fminf(v[k].x, v[k].y), fminf(v[k].z, v[k].w));
        float M = fmaxf(fmaxf(v[k].x, v[k].y), fmaxf(v[k].z, v[k].w));
#pragma unroll
        for (int off = 1; off < 16; off <<= 1) {
            m = fminf(m, __shfl_xor(m, off));
            M = fmaxf(M, __shfl_xor(M, off));
        }
        bmin[k] = m;
        bmax[k] = M;
        float sc = M - m;                              // exact
        tmin = fminf(tmin, sc);
        tmax = fmaxf(tmax, sc);
    }
    tmin = fminf(tmin, __shfl_xor(tmin, 16));
    tmin = fminf(tmin, __shfl_xor(tmin, 32));
    tmax = fmaxf(tmax, __shfl_xor(tmax, 16));
    tmax = fmaxf(tmax, __shfl_xor(tmax, 32));

    if (lane == 0) { smin[wave] = tmin; smax[wave] = tmax; }
    __syncthreads();                                   // covers stbl + smin/smax

    float tbl[16];
#pragma unroll
    for (int i = 0; i < 16; ++i) tbl[i] = stbl[i];     // broadcast LDS reads

    const float s_min  = fminf(fminf(smin[0], smin[1]), fminf(smin[2], smin[3]));
    const float s_max  = fmaxf(fmaxf(smax[0], smax[1]), fmaxf(smax[2], smax[3]));
    const float srange = s_max - s_min;
    const float sden   = srange + 1e-8f;
    const float sqr    = 1.0f / sden;                  // broadcast recip hoist

#pragma unroll
    for (int k = 0; k < 8; ++k) {
        float sc = bmax[k] - bmin[k];
        float sq = rintf(((sc - s_min) * sqr) * 255.0f);   // RNE = np.round
        srec[k]  = s_min + sq / 255.0f * srange;
    }

#pragma unroll
    for (int k = 0; k < 8; ++k) {
        const float bm  = bmin[k];
        const float den = (bmax[k] - bm) + 1e-8f;
        const float s2r = 2.0f / den;                  // == 2*round(1/den) exactly
        const float sr  = srec[k];
        float xv[4] = { v[k].x, v[k].y, v[k].z, v[k].w };
        float wv[4];
#pragma unroll
        for (int c = 0; c < 4; ++c) {
            // XLA default: recip-mul, then SEPARATE subtract (no fma)
            float p  = (xv[c] - bm) * s2r;
            float xn = p - 1.0f;
            // full 16-way argmin, strict '<' keeps FIRST min (np.argmin)
            float best = fabsf(xn - tbl[0]);
            float tsel = tbl[0];
#pragma unroll
            for (int i = 1; i < 16; ++i) {
                float d = fabsf(xn - tbl[i]);
                if (d < best) { best = d; tsel = tbl[i]; }
            }
            wv[c] = (tsel + 1.0f) * 0.5f * sr + bm;    // mul+add, contract off
        }
        float4 r; r.x = wv[0]; r.y = wv[1]; r.z = wv[2]; r.w = wv[3];
        out4[k * 64 + lane] = r;
    }
}

extern "C" void kernel_launch(void* const* d_in, const int* in_sizes, int n_in,
                              void* d_out, int out_size, void* d_ws, size_t ws_size,
                              hipStream_t stream) {
    const float* x = (const float*)d_in[0];
    float* out     = (float*)d_out;
    const int rows = in_sizes[0] / C_COLS;
    nf4_fused_kernel<<<rows, 256, 0, stream>>>(x, out);
}

// Round 7
// 112.419 us; speedup vs baseline: 1.1275x; 1.1275x over previous
//
#include <hip/hip_runtime.h>
#include <cmath>

#define C_COLS 8192

struct NfArgs {
    float tbl[16];   // fp16-exact NF4 levels, as f32
    float kexp;      // -1.702 * log2(e) * qmax  (logistic index estimate)
};

// ---------------------------------------------------------------------------
// Main kernel: one workgroup (256 thr = 4 waves) per row; wave w owns floats
// [w*2048, w*2048+2048); load k: lane holds float4 at elem 256k+4*lane; each
// 16-lane group holds one contiguous 64-elem quant-block.
//
// Decision arithmetic is BIT-IDENTICAL to the passing R5 kernel:
//   x_norm: s2r = 2.0f/den (== 2*round32(1/den)); p=(x-bm)*s2r; xn=p-1.0f
//   argmin: == 16-way f32 |xn-t| scan with strict '<' (first-min). Here:
//     1) estimate index c via logistic Phi approx (abs err 0.0095 => the
//        true scan argmin is ALWAYS in {c-1,c,c+1}; other levels are
//        >= half-gap (~0.04 >> ulp) farther, so they can't win the scan)
//     2) clamp c to [1,14]; read t_{c-1},t_c,t_{c+1} from LDS (16 words =
//        16 distinct banks => broadcast, conflict-free)
//     3) replay the scan on the 3 consecutive candidates in index order
//        with strict '<' => identical result incl. ties
//   scales: recip-hoisted (sc-s_min)*round32(1/sden)*255, rintf (RNE)
// ---------------------------------------------------------------------------
__global__ __launch_bounds__(256) void nf4_main_kernel(
        const float* __restrict__ x, float* __restrict__ out, NfArgs args) {
#pragma clang fp contract(off)
    __shared__ float stbl[16];
    __shared__ float smin[4], smax[4];

    const int row  = blockIdx.x;
    const int wave = threadIdx.x >> 6;
    const int lane = threadIdx.x & 63;
    const long base = (long)row * C_COLS + (long)wave * 2048;
    const float4* __restrict__ xin4 = reinterpret_cast<const float4*>(x + base);
    float4* __restrict__ out4       = reinterpret_cast<float4*>(out + base);

    // issue all global loads first (8 outstanding dwordx4 per lane)
    float4 v[8];
#pragma unroll
    for (int k = 0; k < 8; ++k) v[k] = xin4[k * 64 + lane];   // coalesced

    if (threadIdx.x < 16) stbl[threadIdx.x] = args.tbl[threadIdx.x];

    // ---- block min/max (16-lane group = one 64-elem quant-block) ----
    float bmin[8], bmax[8], srec[8];
    float tmin = 3.4e38f, tmax = -3.4e38f;
#pragma unroll
    for (int k = 0; k < 8; ++k) {
        float m = fminf(fminf(v[k].x, v[k].y), fminf(v[k].z, v[k].w));
        float M = fmaxf(fmaxf(v[k].x, v[k].y), fmaxf(v[k].z, v[k].w));
#pragma unroll
        for (int off = 1; off < 16; off <<= 1) {
            m = fminf(m, __shfl_xor(m, off));
            M = fmaxf(M, __shfl_xor(M, off));
        }
        bmin[k] = m;
        bmax[k] = M;
        float sc = M - m;                              // exact
        tmin = fminf(tmin, sc);
        tmax = fmaxf(tmax, sc);
    }
    tmin = fminf(tmin, __shfl_xor(tmin, 16));
    tmin = fminf(tmin, __shfl_xor(tmin, 32));
    tmax = fmaxf(tmax, __shfl_xor(tmax, 16));
    tmax = fmaxf(tmax, __shfl_xor(tmax, 32));

    if (lane == 0) { smin[wave] = tmin; smax[wave] = tmax; }
    __syncthreads();                                   // covers stbl + smin/smax

    const float s_min  = fminf(fminf(smin[0], smin[1]), fminf(smin[2], smin[3]));
    const float s_max  = fmaxf(fmaxf(smax[0], smax[1]), fmaxf(smax[2], smax[3]));
    const float srange = s_max - s_min;
    const float sden   = srange + 1e-8f;
    const float sqr    = 1.0f / sden;                  // broadcast recip hoist

#pragma unroll
    for (int k = 0; k < 8; ++k) {
        float sc = bmax[k] - bmin[k];
        float sq = rintf(((sc - s_min) * sqr) * 255.0f);   // RNE = np.round
        srec[k]  = s_min + sq / 255.0f * srange;
    }

    const float kexp = args.kexp;
#pragma unroll
    for (int k = 0; k < 8; ++k) {
        const float bm  = bmin[k];
        const float den = (bmax[k] - bm) + 1e-8f;
        const float s2r = 2.0f / den;                  // == 2*round(1/den) exactly
        const float sr  = srec[k];
        float xv[4] = { v[k].x, v[k].y, v[k].z, v[k].w };
        float wv[4];
#pragma unroll
        for (int c = 0; c < 4; ++c) {
            // exact R5 x_norm: recip-mul then SEPARATE subtract (no fma)
            float p  = (xv[c] - bm) * s2r;
            float xn = p - 1.0f;
            // --- index estimate: 16*logistic(1.702*z), z = xn*qmax ---
            float eb = __builtin_amdgcn_exp2f(xn * kexp);
            float f  = 16.0f * __builtin_amdgcn_rcpf(1.0f + eb);
            int ci = (int)f;                           // f in [0,16) -> trunc
            ci = min(max(ci, 1), 14);
            // --- 3-candidate exact replay of the R5 scan ---
            float tm1 = stbl[ci - 1];
            float tc  = stbl[ci];
            float tp1 = stbl[ci + 1];
            float a0 = fabsf(xn - tm1);
            float a1 = fabsf(xn - tc);
            float a2 = fabsf(xn - tp1);
            float t01  = (a1 < a0) ? tc : tm1;         // strict <, index order
            float amin = fminf(a1, a0);
            float tsel = (a2 < amin) ? tp1 : t01;
            wv[c] = (tsel + 1.0f) * 0.5f * sr + bm;    // mul+add, contract off
        }
        float4 r; r.x = wv[0]; r.y = wv[1]; r.z = wv[2]; r.w = wv[3];
        out4[k * 64 + lane] = r;
    }
}

// ---------------------------------------------------------------------------
// Host-side table computation (input-independent, deterministic): f64 ndtri
// via A&S seed + 3 Newton steps on Phi (converges ~1e-13 -> f32 cast is
// libm-variation-proof), f32 normalize, exact fp16 RNE via ulp-scaled rint.
// Same values the passing R5/R6 device path produced.
// ---------------------------------------------------------------------------
static void compute_nf_args(NfArgs* a) {
    double z[16];
    for (int i = 0; i < 16; ++i) {
        double p  = (2.0 * i + 1.0) / 32.0;
        double pl = (p < 0.5) ? p : 1.0 - p;
        double t  = std::sqrt(-2.0 * std::log(pl));
        double zz = t - (2.30753 + 0.27061 * t) / (1.0 + t * (0.99229 + 0.04481 * t));
        if (p < 0.5) zz = -zz;
        for (int it = 0; it < 3; ++it) {
            double Phi = 0.5 * std::erfc(-zz * 0.7071067811865476);
            double phi = 0.3989422804014326779 * std::exp(-0.5 * zz * zz);
            zz -= (Phi - p) / phi;
        }
        z[i] = zz;
    }
    float zf[16], qmax = 0.0f;
    for (int i = 0; i < 16; ++i) { zf[i] = (float)z[i]; qmax = std::fmax(qmax, std::fabs(zf[i])); }
    for (int i = 0; i < 16; ++i) {
        float qn = zf[i] / qmax;                       // IEEE f32 divide
        // exact f32 -> fp16 RNE (values are normal-range fp16)
        double av = std::fabs((double)qn);
        int e; std::frexp(av, &e);
        double ulp = std::ldexp(1.0, e - 11);
        a->tbl[i] = (float)std::copysign(std::rint(av / ulp) * ulp, (double)qn);
    }
    a->kexp = (float)(-1.702 * 1.4426950408889634 * (double)qmax);
}

extern "C" void kernel_launch(void* const* d_in, const int* in_sizes, int n_in,
                              void* d_out, int out_size, void* d_ws, size_t ws_size,
                              hipStream_t stream) {
    const float* x = (const float*)d_in[0];
    float* out     = (float*)d_out;
    const int rows = in_sizes[0] / C_COLS;

    NfArgs args;
    compute_nf_args(&args);                            // host CPU, ~µs, deterministic

    nf4_main_kernel<<<rows, 256, 0, stream>>>(x, out, args);
}